// Round 1
// 204.566 us; speedup vs baseline: 1.0712x; 1.0712x over previous
//
#include <hip/hip_runtime.h>

// Problem constants (fixed by setup_inputs):
//   x: [B=64, D=64, H=32, W=32] fp32   -> N = B*H*W = 65536 rows of D=64
//   codebook: [K=512, D=64] fp32
// Output layout (all fp32, concatenated flat in return order):
//   [0 .. 4194304)        quant_out [B,D,H,W]
//   [4194304]             loss
//   [4194305]             perplexity
//   [4194306 .. +65536)   encoding_indice [B, H*W] (as float)
//   [4259842 .. +32768)   index_program [B,K]
//   [4292610 .. +32768)   softmax_histogram [B,K]

#define OFF_LOSS 4194304
#define OFF_PERP 4194305
#define OFF_ENC  4194306
#define OFF_IP   4259842
#define OFF_SH   4292610

// Workspace layout (floats). Requires ws_size >= 561664*4 B = 2.25 MB.
//   cbT  [4][64][128]  chunk-major transposed codebook (linear-stageable)
//   ce2  [512]         ||e_k||^2 (same 16-lane shfl tree as before)
//   sh partials [1024][512]  per-block softmax-histogram partial
//   loss partials [1024*4]   per-wave loss partial
#define WS_CBT   0
#define WS_CE2   32768
#define WS_SHP   33280
#define WS_LOSS  557568

// R8 changes (perf only; dist/argmin/softmax math bit-identical to R7):
//  - ALL global atomics removed from vq_main. sh -> per-block partials in ws
//    (plain coalesced stores), ip -> rebuilt from enc in vq_reduce (LDS hist),
//    loss -> per-wave partials in ws summed by vq_final. This deletes ~590K
//    device-scope RMW atomics (~128 MB of HBM/fabric traffic).
//  - Codebook transpose + ce2 hoisted to vq_prep (once), so per-chunk staging
//    is 8 linear b128 loads + 8 linear b128 LDS writes; the per-block shuffle
//    trees / scatter writes / XOR swizzle are gone. Linear stride-4 float4
//    LDS reads are already at the 8-cyc bandwidth minimum (no swizzle needed).
//  - hipMemsetAsync dropped: every output region is now fully overwritten.
//  - quant/loss epilogue vectorized: float4 xs reads + float4 quant stores.

__global__ __launch_bounds__(256) void vq_prep(const float* __restrict__ cb,
                                               float* __restrict__ ws)
{
    const int t  = blockIdx.x * 256 + threadIdx.x;   // 0..8191
    const int kg = t >> 4;                           // code 0..511
    const int j  = t & 15;                           // float4 index along D
    const float4 v = ((const float4*)cb)[(kg << 4) + j];
    // ce2: identical expression + 16-lane shfl tree as the old in-kernel path
    float pr = v.x * v.x + v.y * v.y + v.z * v.z + v.w * v.w;
    #pragma unroll
    for (int off = 1; off < 16; off <<= 1) pr += __shfl_xor(pr, off, 16);
    if (j == 0) ws[WS_CE2 + kg] = pr;
    // transposed, chunk-major: ws[WS_CBT + kc*8192 + d*128 + kl]
    const int kc = kg >> 7, kl = kg & 127;
    float* base = ws + WS_CBT + (kc << 13) + (j << 9) + kl;   // d = 4*j
    base[0]   = v.x;
    base[128] = v.y;
    base[256] = v.z;
    base[384] = v.w;
}

__global__ __launch_bounds__(256, 3) void vq_main(
    const float* __restrict__ x, const float* __restrict__ cb,
    const float* __restrict__ wsc,   // cbT + ce2 (read-only region)
    float* __restrict__ wso,         // sh + loss partials (write-only region)
    float* __restrict__ out)
{
    __shared__ float  xs[64 * 64];     // xs[d*64 + r], transposed x tile
    __shared__ float  csT[64 * 128];   // [d][k] for current 128-code chunk
    __shared__ float  ce2[512];        // ||e_k||^2 (fp32)
    __shared__ float  sxx[64];         // ||x_r||^2 (fp32) per row
    __shared__ int    sidx[64];        // argmin code per row

    const int t    = threadIdx.x;
    const int blk  = blockIdx.x;
    const int b    = blk >> 4;          // batch index
    const int row0 = (blk & 15) << 6;   // row offset within batch (H*W space)
    const int tr   = t >> 5;            // 0..7  (row group)
    const int tc   = t & 31;            // 0..31 (col group)

    const float4* cbT4 = (const float4*)(wsc + WS_CBT);

    // ---- stage x tile as float4 (lanes sweep r4: coalesced + conflict-free) ----
    {
        const float4* xb4 = (const float4*)(x + ((size_t)b << 16) + row0);
        #pragma unroll
        for (int p = 0; p < 4; ++p) {
            const int fi = (p << 8) + t;      // 0..1023
            const int d  = fi >> 4;
            const int r4 = fi & 15;
            *(float4*)&xs[(d << 6) + (r4 << 2)] = xb4[(d << 8) + r4];
        }
    }
    // ---- stage ce2 from ws ----
    if (t < 128) ((float4*)ce2)[t] = ((const float4*)(wsc + WS_CE2))[t];

    // ---- prefetch chunk 0 of transposed codebook into registers ----
    float4 pv[8];
    #pragma unroll
    for (int p = 0; p < 8; ++p) pv[p] = cbT4[(p << 8) + t];

    __syncthreads();
    // ---- ||x_r||^2 fp32, sequential fmaf over d (bit-exact vs R7) ----
    if (t < 64) {
        float s = 0.f;
        for (int d = 0; d < 64; ++d) { const float v = xs[(d << 6) + t]; s = fmaf(v, v, s); }
        sxx[t] = s;
    }

    float acc[8][16];
    #pragma unroll
    for (int i = 0; i < 8; ++i)
        #pragma unroll
        for (int c = 0; c < 16; ++c) acc[i][c] = 0.f;

    // ---- GEMM: 4 chunks of 128 codes ----
    #pragma unroll
    for (int kc = 0; kc < 4; ++kc) {
        __syncthreads();   // csT free (prior chunk's reads done); sxx visible
        // stage csT linearly from registers (pre-transposed in ws)
        #pragma unroll
        for (int p = 0; p < 8; ++p) ((float4*)csT)[(p << 8) + t] = pv[p];
        // issue next chunk's global loads now; they complete during the d-loop
        if (kc < 3) {
            #pragma unroll
            for (int p = 0; p < 8; ++p) pv[p] = cbT4[((kc + 1) << 11) + (p << 8) + t];
        }
        __syncthreads();   // csT ready
        #pragma unroll 2
        for (int db = 0; db < 16; ++db) {
            const float* cbase = &csT[(db << 9) + (tc << 2)];
            #pragma unroll
            for (int j = 0; j < 4; ++j) {
                const int d = (db << 2) + j;
                const float4 a0 = *(const float4*)&xs[(d << 6) + (tr << 2)];
                const float4 a1 = *(const float4*)&xs[(d << 6) + (tr << 2) + 32];
                const float4 bq = *(const float4*)&cbase[j << 7];
                const float av[8] = {a0.x, a0.y, a0.z, a0.w, a1.x, a1.y, a1.z, a1.w};
                const float bv[4] = {bq.x, bq.y, bq.z, bq.w};
                #pragma unroll
                for (int i = 0; i < 8; ++i)
                    #pragma unroll
                    for (int jj = 0; jj < 4; ++jj)
                        acc[i][(kc << 2) + jj] = fmaf(av[i], bv[jj], acc[i][(kc << 2) + jj]);
            }
        }
    }

    // ---- epilogue: ref-exact fp32 dist; per-row argmin + softmax(-dist) ----
    float* enc = out + OFF_ENC;
    float invz[8];

    #pragma unroll
    for (int i = 0; i < 8; ++i) {
        const int row = ((i >> 2) << 5) + (tr << 2) + (i & 3);
        const float xxr = sxx[row];
        float m = 1e30f; int bk = 0;
        #pragma unroll
        for (int c = 0; c < 16; ++c) {
            const int k = ((c >> 2) << 7) + (tc << 2) + (c & 3);   // ascending in c
            const float t1   = xxr + ce2[k];          // fp32 round @ ulp(~64)
            const float dist = t1 - 2.f * acc[i][c];  // fp32 round @ ulp(~64)
            acc[i][c] = dist;
            if (dist < m) { m = dist; bk = k; }       // strict <: lowest k kept
        }
        // lexicographic (min dist, min k) butterfly across the 32 lanes of row
        #pragma unroll
        for (int off = 1; off < 32; off <<= 1) {
            const float mo = __shfl_xor(m, off, 32);
            const int   ko = __shfl_xor(bk, off, 32);
            if (mo < m || (mo == m && ko < bk)) { m = mo; bk = ko; }
        }
        float z = 0.f;
        #pragma unroll
        for (int c = 0; c < 16; ++c) {
            const float e = __expf(m - acc[i][c]);    // softmax(-dist), shifted
            acc[i][c] = e; z += e;
        }
        #pragma unroll
        for (int off = 1; off < 32; off <<= 1) z += __shfl_xor(z, off, 32);
        invz[i] = 1.f / z;

        if (tc == 0) {
            sidx[row] = bk;
            enc[((size_t)b << 10) + row0 + row] = (float)bk;
        }
    }

    __syncthreads();   // all csT reads done; sidx visible

    // ---- softmax histogram: block-reduce in LDS (alias csT), partial to ws ----
    float* shist = csT;
    shist[t] = 0.f; shist[t + 256] = 0.f;
    __syncthreads();
    #pragma unroll
    for (int c = 0; c < 16; ++c) {
        const int k = ((c >> 2) << 7) + (tc << 2) + (c & 3);
        float cs = 0.f;
        #pragma unroll
        for (int i = 0; i < 8; ++i) cs += acc[i][c] * invz[i];
        atomicAdd(&shist[k], cs);
    }
    __syncthreads();
    {
        float* wsh = wso + WS_SHP + ((size_t)blk << 9);
        wsh[t]       = shist[t];
        wsh[t + 256] = shist[t + 256];
    }

    // ---- quantized output + loss partial (from sidx), vectorized ----
    const int r4 = (t & 15) << 2;
    const int dq = t >> 4;                 // 0..15
    const int c0 = sidx[r4], c1 = sidx[r4 + 1], c2 = sidx[r4 + 2], c3 = sidx[r4 + 3];
    float lsum = 0.f;
    #pragma unroll
    for (int p = 0; p < 4; ++p) {
        const int d = (p << 4) + dq;
        float4 q;
        q.x = cb[(c0 << 6) + d];
        q.y = cb[(c1 << 6) + d];
        q.z = cb[(c2 << 6) + d];
        q.w = cb[(c3 << 6) + d];
        const float4 xv = *(const float4*)&xs[(d << 6) + r4];
        const float d0 = q.x - xv.x, d1 = q.y - xv.y, d2 = q.z - xv.z, d3 = q.w - xv.w;
        lsum = fmaf(d0, d0, lsum); lsum = fmaf(d1, d1, lsum);
        lsum = fmaf(d2, d2, lsum); lsum = fmaf(d3, d3, lsum);
        *(float4*)&out[(((size_t)(b << 6) + d) << 10) + row0 + r4] = q;
    }
    #pragma unroll
    for (int off = 1; off < 64; off <<= 1) lsum += __shfl_xor(lsum, off, 64);
    if ((t & 63) == 0) wso[WS_LOSS + (blk << 2) + (t >> 6)] = lsum;
}

// per-batch: sum 16 sh partials; rebuild ip histogram from enc indices
__global__ __launch_bounds__(512) void vq_reduce(const float* __restrict__ ws,
                                                 float* __restrict__ out)
{
    __shared__ int hist[512];
    const int b = blockIdx.x, t = threadIdx.x;
    const float* p = ws + WS_SHP + ((size_t)b << 13) + t;   // b*16*512
    float s = 0.f;
    #pragma unroll
    for (int j = 0; j < 16; ++j) s += p[j << 9];
    out[OFF_SH + (b << 9) + t] = s;
    hist[t] = 0;
    __syncthreads();
    const float* enc = out + OFF_ENC + ((size_t)b << 10);
    const int ca = (int)enc[t];
    const int cbn = (int)enc[t + 512];
    atomicAdd(&hist[ca], 1);
    atomicAdd(&hist[cbn], 1);
    __syncthreads();
    out[OFF_IP + (b << 9) + t] = (float)hist[t];
}

// loss sum + perplexity from per-batch code counts (512 threads, one k each)
__global__ __launch_bounds__(512) void vq_final(const float* __restrict__ ws,
                                                float* __restrict__ out)
{
    __shared__ float red[8], red2[8];
    const int t = threadIdx.x;
    const float* ip = out + OFF_IP;
    float c0 = 0.f, c1 = 0.f, c2 = 0.f, c3 = 0.f;
    #pragma unroll
    for (int bb = 0; bb < 64; bb += 4) {
        c0 += ip[((bb + 0) << 9) + t];
        c1 += ip[((bb + 1) << 9) + t];
        c2 += ip[((bb + 2) << 9) + t];
        c3 += ip[((bb + 3) << 9) + t];
    }
    const float c = (c0 + c1) + (c2 + c3);
    const float pav = c * (1.0f / 65536.f);
    float h = pav * logf(pav + 1e-10f);
    // loss partials: 4096 floats
    const float* wl = ws + WS_LOSS;
    float ls = 0.f;
    #pragma unroll
    for (int j = 0; j < 8; ++j) ls += wl[(j << 9) + t];
    #pragma unroll
    for (int off = 1; off < 64; off <<= 1) {
        h  += __shfl_xor(h, off, 64);
        ls += __shfl_xor(ls, off, 64);
    }
    if ((t & 63) == 0) { red[t >> 6] = h; red2[t >> 6] = ls; }
    __syncthreads();
    if (t == 0) {
        float H = 0.f, L = 0.f;
        #pragma unroll
        for (int w = 0; w < 8; ++w) { H += red[w]; L += red2[w]; }
        out[OFF_PERP] = expf(-H);
        out[OFF_LOSS] = L * (1.25f / 4194304.f);
    }
}

extern "C" void kernel_launch(void* const* d_in, const int* in_sizes, int n_in,
                              void* d_out, int out_size, void* d_ws, size_t ws_size,
                              hipStream_t stream)
{
    const float* x  = (const float*)d_in[0];
    const float* cb = (const float*)d_in[1];
    float* out = (float*)d_out;
    float* ws  = (float*)d_ws;
    (void)ws_size;   // requires >= 2.25 MB (561664 floats)

    // No memset needed: enc/quant are overwritten by vq_main, sh/ip by
    // vq_reduce, loss/perp by vq_final. No global atomics anywhere.
    vq_prep  <<<32,   256, 0, stream>>>(cb, ws);
    vq_main  <<<1024, 256, 0, stream>>>(x, cb, ws, ws, out);
    vq_reduce<<<64,   512, 0, stream>>>(ws, out);
    vq_final <<<1,    512, 0, stream>>>(ws, out);
}

// Round 2
// 190.157 us; speedup vs baseline: 1.1524x; 1.0758x over previous
//
#include <hip/hip_runtime.h>

// Problem constants (fixed by setup_inputs):
//   x: [B=64, D=64, H=32, W=32] fp32   -> N = B*H*W = 65536 rows of D=64
//   codebook: [K=512, D=64] fp32
// Output layout (all fp32, concatenated flat in return order):
//   [0 .. 4194304)        quant_out [B,D,H,W]
//   [4194304]             loss
//   [4194305]             perplexity
//   [4194306 .. +65536)   encoding_indice [B, H*W] (as float)
//   [4259842 .. +32768)   index_program [B,K]
//   [4292610 .. +32768)   softmax_histogram [B,K]

#define OFF_LOSS 4194304
#define OFF_PERP 4194305
#define OFF_ENC  4194306
#define OFF_IP   4259842
#define OFF_SH   4292610

// Workspace layout (floats). Requires ws_size >= 561664*4 B = 2.25 MB.
//   cbT  [4][64][128]  chunk-major transposed codebook (linear-stageable)
//   ce2  [512]         ||e_k||^2 (same 16-lane shfl tree as before)
//   sh partials [1024][512]  per-block softmax-histogram partial
//   loss partials [1024*4]   per-wave loss partial
#define WS_CBT   0
#define WS_CE2   32768
#define WS_SHP   33280
#define WS_LOSS  557568

// R9 change (perf only; all math bit-identical to R8):
//  - __launch_bounds__(256,3) -> (256,2). The (256,3) bound capped the
//    allocator at ~168 VGPRs while the working set (acc[8][16]=128 regs +
//    pv[8]=32 + temps) needs ~200, so the accumulator tile spilled to
//    scratch. Scratch = global memory: the spill round-trips explain the
//    entire unexplained 168 MB WRITE + 48 MB FETCH excess and the 35%
//    VALUBusy ceiling. (256,2) raises the cap to 256 VGPRs -> no spill,
//    2 blocks/CU resident (the 3rd block never helped: waves were
//    stalled on their own spill traffic, not latency-starved).

__global__ __launch_bounds__(256) void vq_prep(const float* __restrict__ cb,
                                               float* __restrict__ ws)
{
    const int t  = blockIdx.x * 256 + threadIdx.x;   // 0..8191
    const int kg = t >> 4;                           // code 0..511
    const int j  = t & 15;                           // float4 index along D
    const float4 v = ((const float4*)cb)[(kg << 4) + j];
    // ce2: identical expression + 16-lane shfl tree as the old in-kernel path
    float pr = v.x * v.x + v.y * v.y + v.z * v.z + v.w * v.w;
    #pragma unroll
    for (int off = 1; off < 16; off <<= 1) pr += __shfl_xor(pr, off, 16);
    if (j == 0) ws[WS_CE2 + kg] = pr;
    // transposed, chunk-major: ws[WS_CBT + kc*8192 + d*128 + kl]
    const int kc = kg >> 7, kl = kg & 127;
    float* base = ws + WS_CBT + (kc << 13) + (j << 9) + kl;   // d = 4*j
    base[0]   = v.x;
    base[128] = v.y;
    base[256] = v.z;
    base[384] = v.w;
}

__global__ __launch_bounds__(256, 2) void vq_main(
    const float* __restrict__ x, const float* __restrict__ cb,
    const float* __restrict__ wsc,   // cbT + ce2 (read-only region)
    float* __restrict__ wso,         // sh + loss partials (write-only region)
    float* __restrict__ out)
{
    __shared__ float  xs[64 * 64];     // xs[d*64 + r], transposed x tile
    __shared__ float  csT[64 * 128];   // [d][k] for current 128-code chunk
    __shared__ float  ce2[512];        // ||e_k||^2 (fp32)
    __shared__ float  sxx[64];         // ||x_r||^2 (fp32) per row
    __shared__ int    sidx[64];        // argmin code per row

    const int t    = threadIdx.x;
    const int blk  = blockIdx.x;
    const int b    = blk >> 4;          // batch index
    const int row0 = (blk & 15) << 6;   // row offset within batch (H*W space)
    const int tr   = t >> 5;            // 0..7  (row group)
    const int tc   = t & 31;            // 0..31 (col group)

    const float4* cbT4 = (const float4*)(wsc + WS_CBT);

    // ---- stage x tile as float4 (lanes sweep r4: coalesced + conflict-free) ----
    {
        const float4* xb4 = (const float4*)(x + ((size_t)b << 16) + row0);
        #pragma unroll
        for (int p = 0; p < 4; ++p) {
            const int fi = (p << 8) + t;      // 0..1023
            const int d  = fi >> 4;
            const int r4 = fi & 15;
            *(float4*)&xs[(d << 6) + (r4 << 2)] = xb4[(d << 8) + r4];
        }
    }
    // ---- stage ce2 from ws ----
    if (t < 128) ((float4*)ce2)[t] = ((const float4*)(wsc + WS_CE2))[t];

    // ---- prefetch chunk 0 of transposed codebook into registers ----
    float4 pv[8];
    #pragma unroll
    for (int p = 0; p < 8; ++p) pv[p] = cbT4[(p << 8) + t];

    __syncthreads();
    // ---- ||x_r||^2 fp32, sequential fmaf over d (bit-exact vs R8) ----
    if (t < 64) {
        float s = 0.f;
        for (int d = 0; d < 64; ++d) { const float v = xs[(d << 6) + t]; s = fmaf(v, v, s); }
        sxx[t] = s;
    }

    float acc[8][16];
    #pragma unroll
    for (int i = 0; i < 8; ++i)
        #pragma unroll
        for (int c = 0; c < 16; ++c) acc[i][c] = 0.f;

    // ---- GEMM: 4 chunks of 128 codes ----
    #pragma unroll
    for (int kc = 0; kc < 4; ++kc) {
        __syncthreads();   // csT free (prior chunk's reads done); sxx visible
        // stage csT linearly from registers (pre-transposed in ws)
        #pragma unroll
        for (int p = 0; p < 8; ++p) ((float4*)csT)[(p << 8) + t] = pv[p];
        // issue next chunk's global loads now; they complete during the d-loop
        if (kc < 3) {
            #pragma unroll
            for (int p = 0; p < 8; ++p) pv[p] = cbT4[((kc + 1) << 11) + (p << 8) + t];
        }
        __syncthreads();   // csT ready
        #pragma unroll 2
        for (int db = 0; db < 16; ++db) {
            const float* cbase = &csT[(db << 9) + (tc << 2)];
            #pragma unroll
            for (int j = 0; j < 4; ++j) {
                const int d = (db << 2) + j;
                const float4 a0 = *(const float4*)&xs[(d << 6) + (tr << 2)];
                const float4 a1 = *(const float4*)&xs[(d << 6) + (tr << 2) + 32];
                const float4 bq = *(const float4*)&cbase[j << 7];
                const float av[8] = {a0.x, a0.y, a0.z, a0.w, a1.x, a1.y, a1.z, a1.w};
                const float bv[4] = {bq.x, bq.y, bq.z, bq.w};
                #pragma unroll
                for (int i = 0; i < 8; ++i)
                    #pragma unroll
                    for (int jj = 0; jj < 4; ++jj)
                        acc[i][(kc << 2) + jj] = fmaf(av[i], bv[jj], acc[i][(kc << 2) + jj]);
            }
        }
    }

    // ---- epilogue: ref-exact fp32 dist; per-row argmin + softmax(-dist) ----
    float* enc = out + OFF_ENC;
    float invz[8];

    #pragma unroll
    for (int i = 0; i < 8; ++i) {
        const int row = ((i >> 2) << 5) + (tr << 2) + (i & 3);
        const float xxr = sxx[row];
        float m = 1e30f; int bk = 0;
        #pragma unroll
        for (int c = 0; c < 16; ++c) {
            const int k = ((c >> 2) << 7) + (tc << 2) + (c & 3);   // ascending in c
            const float t1   = xxr + ce2[k];          // fp32 round @ ulp(~64)
            const float dist = t1 - 2.f * acc[i][c];  // fp32 round @ ulp(~64)
            acc[i][c] = dist;
            if (dist < m) { m = dist; bk = k; }       // strict <: lowest k kept
        }
        // lexicographic (min dist, min k) butterfly across the 32 lanes of row
        #pragma unroll
        for (int off = 1; off < 32; off <<= 1) {
            const float mo = __shfl_xor(m, off, 32);
            const int   ko = __shfl_xor(bk, off, 32);
            if (mo < m || (mo == m && ko < bk)) { m = mo; bk = ko; }
        }
        float z = 0.f;
        #pragma unroll
        for (int c = 0; c < 16; ++c) {
            const float e = __expf(m - acc[i][c]);    // softmax(-dist), shifted
            acc[i][c] = e; z += e;
        }
        #pragma unroll
        for (int off = 1; off < 32; off <<= 1) z += __shfl_xor(z, off, 32);
        invz[i] = 1.f / z;

        if (tc == 0) {
            sidx[row] = bk;
            enc[((size_t)b << 10) + row0 + row] = (float)bk;
        }
    }

    __syncthreads();   // all csT reads done; sidx visible

    // ---- softmax histogram: block-reduce in LDS (alias csT), partial to ws ----
    float* shist = csT;
    shist[t] = 0.f; shist[t + 256] = 0.f;
    __syncthreads();
    #pragma unroll
    for (int c = 0; c < 16; ++c) {
        const int k = ((c >> 2) << 7) + (tc << 2) + (c & 3);
        float cs = 0.f;
        #pragma unroll
        for (int i = 0; i < 8; ++i) cs += acc[i][c] * invz[i];
        atomicAdd(&shist[k], cs);
    }
    __syncthreads();
    {
        float* wsh = wso + WS_SHP + ((size_t)blk << 9);
        wsh[t]       = shist[t];
        wsh[t + 256] = shist[t + 256];
    }

    // ---- quantized output + loss partial (from sidx), vectorized ----
    const int r4 = (t & 15) << 2;
    const int dq = t >> 4;                 // 0..15
    const int c0 = sidx[r4], c1 = sidx[r4 + 1], c2 = sidx[r4 + 2], c3 = sidx[r4 + 3];
    float lsum = 0.f;
    #pragma unroll
    for (int p = 0; p < 4; ++p) {
        const int d = (p << 4) + dq;
        float4 q;
        q.x = cb[(c0 << 6) + d];
        q.y = cb[(c1 << 6) + d];
        q.z = cb[(c2 << 6) + d];
        q.w = cb[(c3 << 6) + d];
        const float4 xv = *(const float4*)&xs[(d << 6) + r4];
        const float d0 = q.x - xv.x, d1 = q.y - xv.y, d2 = q.z - xv.z, d3 = q.w - xv.w;
        lsum = fmaf(d0, d0, lsum); lsum = fmaf(d1, d1, lsum);
        lsum = fmaf(d2, d2, lsum); lsum = fmaf(d3, d3, lsum);
        *(float4*)&out[(((size_t)(b << 6) + d) << 10) + row0 + r4] = q;
    }
    #pragma unroll
    for (int off = 1; off < 64; off <<= 1) lsum += __shfl_xor(lsum, off, 64);
    if ((t & 63) == 0) wso[WS_LOSS + (blk << 2) + (t >> 6)] = lsum;
}

// per-batch: sum 16 sh partials; rebuild ip histogram from enc indices
__global__ __launch_bounds__(512) void vq_reduce(const float* __restrict__ ws,
                                                 float* __restrict__ out)
{
    __shared__ int hist[512];
    const int b = blockIdx.x, t = threadIdx.x;
    const float* p = ws + WS_SHP + ((size_t)b << 13) + t;   // b*16*512
    float s = 0.f;
    #pragma unroll
    for (int j = 0; j < 16; ++j) s += p[j << 9];
    out[OFF_SH + (b << 9) + t] = s;
    hist[t] = 0;
    __syncthreads();
    const float* enc = out + OFF_ENC + ((size_t)b << 10);
    const int ca = (int)enc[t];
    const int cbn = (int)enc[t + 512];
    atomicAdd(&hist[ca], 1);
    atomicAdd(&hist[cbn], 1);
    __syncthreads();
    out[OFF_IP + (b << 9) + t] = (float)hist[t];
}

// loss sum + perplexity from per-batch code counts (512 threads, one k each)
__global__ __launch_bounds__(512) void vq_final(const float* __restrict__ ws,
                                                float* __restrict__ out)
{
    __shared__ float red[8], red2[8];
    const int t = threadIdx.x;
    const float* ip = out + OFF_IP;
    float c0 = 0.f, c1 = 0.f, c2 = 0.f, c3 = 0.f;
    #pragma unroll
    for (int bb = 0; bb < 64; bb += 4) {
        c0 += ip[((bb + 0) << 9) + t];
        c1 += ip[((bb + 1) << 9) + t];
        c2 += ip[((bb + 2) << 9) + t];
        c3 += ip[((bb + 3) << 9) + t];
    }
    const float c = (c0 + c1) + (c2 + c3);
    const float pav = c * (1.0f / 65536.f);
    float h = pav * logf(pav + 1e-10f);
    // loss partials: 4096 floats
    const float* wl = ws + WS_LOSS;
    float ls = 0.f;
    #pragma unroll
    for (int j = 0; j < 8; ++j) ls += wl[(j << 9) + t];
    #pragma unroll
    for (int off = 1; off < 64; off <<= 1) {
        h  += __shfl_xor(h, off, 64);
        ls += __shfl_xor(ls, off, 64);
    }
    if ((t & 63) == 0) { red[t >> 6] = h; red2[t >> 6] = ls; }
    __syncthreads();
    if (t == 0) {
        float H = 0.f, L = 0.f;
        #pragma unroll
        for (int w = 0; w < 8; ++w) { H += red[w]; L += red2[w]; }
        out[OFF_PERP] = expf(-H);
        out[OFF_LOSS] = L * (1.25f / 4194304.f);
    }
}

extern "C" void kernel_launch(void* const* d_in, const int* in_sizes, int n_in,
                              void* d_out, int out_size, void* d_ws, size_t ws_size,
                              hipStream_t stream)
{
    const float* x  = (const float*)d_in[0];
    const float* cb = (const float*)d_in[1];
    float* out = (float*)d_out;
    float* ws  = (float*)d_ws;
    (void)ws_size;   // requires >= 2.25 MB (561664 floats)

    // No memset needed: enc/quant are overwritten by vq_main, sh/ip by
    // vq_reduce, loss/perp by vq_final. No global atomics anywhere.
    vq_prep  <<<32,   256, 0, stream>>>(cb, ws);
    vq_main  <<<1024, 256, 0, stream>>>(x, cb, ws, ws, out);
    vq_reduce<<<64,   512, 0, stream>>>(ws, out);
    vq_final <<<1,    512, 0, stream>>>(ws, out);
}